// Round 1
// baseline (762.235 us; speedup 1.0000x reference)
//
#include <hip/hip_runtime.h>
#include <math.h>

// QTGNN: GRU(10 steps, hidden16) -> QGAT layer1 -> QGAT layer2 -> linear head.
// N=10000 nodes, E=320000 edges (+N self loops). All fp32.
// Structure: 7 kernels on one stream; quantum circuit fully in registers.

#define GH 16
#define SEQ 10
#define PI_F 3.14159265358979323846f

__device__ __forceinline__ float sigmoidf_(float x) { return 1.0f / (1.0f + expf(-x)); }

// monotonic float<->uint mapping for atomicMax on signed floats
__device__ __forceinline__ unsigned fkey(float f) {
    unsigned u = __float_as_uint(f);
    return (u & 0x80000000u) ? ~u : (u | 0x80000000u);
}
__device__ __forceinline__ float funkey(unsigned k) {
    return __uint_as_float((k & 0x80000000u) ? (k ^ 0x80000000u) : ~k);
}

// ---------------- GRU + layer-1 ELU projection ----------------
__global__ __launch_bounds__(256) void k_gru(
    const float* __restrict__ x, const float* __restrict__ W_ih,
    const float* __restrict__ W_hh, const float* __restrict__ b_ih,
    const float* __restrict__ b_hh, const float* __restrict__ p1W,
    const float* __restrict__ p1b, float* __restrict__ h1, int N)
{
    __shared__ float sW[48 * 16];
    __shared__ float swin[48], sbih[48], sbhh[48];
    __shared__ float sp1W[4 * 19], sp1b[4];
    for (int i = threadIdx.x; i < 48 * 16; i += blockDim.x) sW[i] = W_hh[i];
    if (threadIdx.x < 48) {
        swin[threadIdx.x] = W_ih[threadIdx.x];
        sbih[threadIdx.x] = b_ih[threadIdx.x];
        sbhh[threadIdx.x] = b_hh[threadIdx.x];
    }
    for (int i = threadIdx.x; i < 76; i += blockDim.x) sp1W[i] = p1W[i];
    if (threadIdx.x < 4) sp1b[threadIdx.x] = p1b[threadIdx.x];
    __syncthreads();

    int n = blockIdx.x * blockDim.x + threadIdx.x;
    if (n >= N) return;

    float xv[13];
#pragma unroll
    for (int t = 0; t < 13; ++t) xv[t] = x[n * 13 + t];

    float h[GH];
#pragma unroll
    for (int j = 0; j < GH; ++j) h[j] = 0.f;

    for (int t = 0; t < SEQ; ++t) {
        float xt = xv[t];
        float nn[GH], zz[GH];
#pragma unroll
        for (int j = 0; j < GH; ++j) {
            float ghr = sbhh[j], ghz = sbhh[16 + j], ghn = sbhh[32 + j];
#pragma unroll
            for (int k = 0; k < GH; ++k) {
                float hk = h[k];
                ghr += sW[j * 16 + k] * hk;
                ghz += sW[(16 + j) * 16 + k] * hk;
                ghn += sW[(32 + j) * 16 + k] * hk;
            }
            float r = sigmoidf_(xt * swin[j] + sbih[j] + ghr);
            float z = sigmoidf_(xt * swin[16 + j] + sbih[16 + j] + ghz);
            float nv = tanhf(xt * swin[32 + j] + sbih[32 + j] + r * ghn);
            nn[j] = nv; zz[j] = z;
        }
#pragma unroll
        for (int j = 0; j < GH; ++j) h[j] = (1.f - zz[j]) * nn[j] + zz[j] * h[j];
    }
    // proj1: elu([h, x[10:13]] @ p1W.T + p1b)
#pragma unroll
    for (int w = 0; w < 4; ++w) {
        float s = sp1b[w];
#pragma unroll
        for (int k = 0; k < GH; ++k) s += h[k] * sp1W[w * 19 + k];
        s += xv[10] * sp1W[w * 19 + 16] + xv[11] * sp1W[w * 19 + 17] + xv[12] * sp1W[w * 19 + 18];
        h1[n * 4 + w] = (s > 0.f) ? s : expm1f(s);
    }
}

// ---------------- attention logits + global max ----------------
__global__ __launch_bounds__(256) void k_alpha(
    const int* __restrict__ ei, const float* __restrict__ ea,
    const float* __restrict__ h, const float* __restrict__ Wa,
    float* __restrict__ alpha, unsigned* __restrict__ gmax, int E, int N)
{
    int e = blockIdx.x * blockDim.x + threadIdx.x;
    int EN = E + N;
    float a = -INFINITY;
    if (e < EN) {
        int src = (e < E) ? ei[e] : (e - E);
        int dst = (e < E) ? ei[E + e] : (e - E);
        float eav = (e < E) ? ea[e] : 1.0f;
        float s0 = 0.f;
#pragma unroll
        for (int k = 0; k < 4; ++k) s0 += h[src * 4 + k] * Wa[k] + h[dst * 4 + k] * Wa[4 + k];
        s0 = (s0 > 0.f) ? s0 : 0.2f * s0;
        a = s0 * fabsf(eav);
        alpha[e] = a;
    }
    float m = a;
#pragma unroll
    for (int off = 32; off; off >>= 1) m = fmaxf(m, __shfl_down(m, off));
    if ((threadIdx.x & 63) == 0) atomicMax(gmax, fkey(m));
}

// ---------------- quantum gate helpers (all indices compile-time) ----------------
template <int STR>
__device__ __forceinline__ void ry_g(float (&sr)[16], float (&si)[16], float c, float s) {
#pragma unroll
    for (int i0 = 0; i0 < 16; ++i0) {
        if (i0 & STR) continue;
        int i1 = i0 | STR;
        float a0r = sr[i0], a0i = si[i0], a1r = sr[i1], a1i = si[i1];
        sr[i0] = c * a0r - s * a1r; si[i0] = c * a0i - s * a1i;
        sr[i1] = s * a0r + c * a1r; si[i1] = s * a0i + c * a1i;
    }
}
template <int STR>
__device__ __forceinline__ void rz_g(float (&sr)[16], float (&si)[16], float c, float s) {
#pragma unroll
    for (int i = 0; i < 16; ++i) {
        float r = sr[i], im = si[i];
        if (i & STR) { sr[i] = r * c - im * s; si[i] = im * c + r * s; }
        else         { sr[i] = r * c + im * s; si[i] = im * c - r * s; }
    }
}
template <int SC, int ST>
__device__ __forceinline__ void cnot_g(float (&sr)[16], float (&si)[16]) {
#pragma unroll
    for (int i = 0; i < 16; ++i) {
        if ((i & SC) && !(i & ST)) {
            int j = i | ST;
            float tr = sr[i], ti = si[i];
            sr[i] = sr[j]; si[i] = si[j]; sr[j] = tr; si[j] = ti;
        }
    }
}

// ---------------- per-edge message: softmax-numerator x qcircuit, atomic aggregate ----------------
__global__ __launch_bounds__(256) void k_msg(
    const int* __restrict__ ei, const float* __restrict__ ea,
    const float* __restrict__ h, const float* __restrict__ alpha,
    const unsigned* __restrict__ gmax, const float* __restrict__ qw,
    float* __restrict__ S, float* __restrict__ dsum, int E, int N)
{
    int e = blockIdx.x * blockDim.x + threadIdx.x;
    int EN = E + N;
    if (e >= EN) return;
    int src = (e < E) ? ei[e] : (e - E);
    int dst = (e < E) ? ei[E + e] : (e - E);
    float eav = (e < E) ? ea[e] : 1.0f;

    float gm = funkey(*gmax);
    float aexp = expf(alpha[e] - gm);

    // per-edge gate angles: RY(tanh(h[src,k])*pi) on wire k, RY(tanh(ea)*pi) on wire 0
    float ic[5], is_[5];
#pragma unroll
    for (int k = 0; k < 4; ++k) {
        float th = tanhf(h[src * 4 + k]) * PI_F;
        float sv, cv; sincosf(0.5f * th, &sv, &cv);
        ic[k] = cv; is_[k] = sv;
    }
    {
        float th = tanhf(eav) * PI_F;
        float sv, cv; sincosf(0.5f * th, &sv, &cv);
        ic[4] = cv; is_[4] = sv;
    }
    // weight gates: qw[(r*2+d)*2 + {0:RY,1:RZ}]
    float wyc[6], wys[6], wzc[6], wzs[6];
#pragma unroll
    for (int rd = 0; rd < 6; ++rd) {
        float sy, cy; sincosf(0.5f * qw[rd * 2 + 0], &sy, &cy); wyc[rd] = cy; wys[rd] = sy;
        float sz, cz; sincosf(0.5f * qw[rd * 2 + 1], &sz, &cz); wzc[rd] = cz; wzs[rd] = sz;
    }

    float sr[16], si[16];
#pragma unroll
    for (int i = 0; i < 16; ++i) { sr[i] = 0.f; si[i] = 0.f; }
    sr[0] = 1.f;

#pragma unroll
    for (int r = 0; r < 3; ++r) {
        ry_g<8>(sr, si, ic[0], is_[0]);
        ry_g<4>(sr, si, ic[1], is_[1]);
        ry_g<2>(sr, si, ic[2], is_[2]);
        ry_g<1>(sr, si, ic[3], is_[3]);
        ry_g<8>(sr, si, ic[4], is_[4]);
#pragma unroll
        for (int d = 0; d < 2; ++d) {
            int rd = r * 2 + d;
            float cy = wyc[rd], sy = wys[rd], cz = wzc[rd], sz = wzs[rd];
            ry_g<8>(sr, si, cy, sy); rz_g<8>(sr, si, cz, sz);
            ry_g<4>(sr, si, cy, sy); rz_g<4>(sr, si, cz, sz);
            ry_g<2>(sr, si, cy, sy); rz_g<2>(sr, si, cz, sz);
            ry_g<1>(sr, si, cy, sy); rz_g<1>(sr, si, cz, sz);
            if (d == 0) { cnot_g<8, 4>(sr, si); cnot_g<2, 1>(sr, si); }
            else        { cnot_g<4, 2>(sr, si); }
        }
    }

    float p[16];
#pragma unroll
    for (int i = 0; i < 16; ++i) p[i] = sr[i] * sr[i] + si[i] * si[i];
#pragma unroll
    for (int w = 0; w < 4; ++w) {
        const int STR = 8 >> w;
        float z = 0.f;
#pragma unroll
        for (int i = 0; i < 16; ++i) z += (i & STR) ? -p[i] : p[i];
        atomicAdd(&S[dst * 4 + w], aexp * z);
    }
    atomicAdd(&dsum[dst], aexp);
}

// ---------------- node update layer1: norm + residual + LN + relu + proj2 ----------------
__global__ __launch_bounds__(256) void k_node1(
    const float* __restrict__ S, const float* __restrict__ dsum,
    const float* __restrict__ h1, const float* __restrict__ g,
    const float* __restrict__ be, const float* __restrict__ p2W,
    const float* __restrict__ p2b, float* __restrict__ h2, int N)
{
    int n = blockIdx.x * blockDim.x + threadIdx.x;
    if (n >= N) return;
    float dn = dsum[n] + 1e-8f;
    float v[4];
#pragma unroll
    for (int k = 0; k < 4; ++k) v[k] = S[n * 4 + k] / dn + h1[n * 4 + k];
    float mu = 0.25f * (v[0] + v[1] + v[2] + v[3]);
    float var = 0.f;
#pragma unroll
    for (int k = 0; k < 4; ++k) { float t = v[k] - mu; var += t * t; }
    var *= 0.25f;
    float rs = 1.0f / sqrtf(var + 1e-5f);
    float y[4];
#pragma unroll
    for (int k = 0; k < 4; ++k) {
        float t = (v[k] - mu) * rs * g[k] + be[k];
        y[k] = fmaxf(t, 0.f);  // relu between layers
    }
#pragma unroll
    for (int w = 0; w < 4; ++w) {
        float s = p2b[w];
#pragma unroll
        for (int k = 0; k < 4; ++k) s += y[k] * p2W[w * 4 + k];
        h2[n * 4 + w] = (s > 0.f) ? s : expm1f(s);
    }
}

// ---------------- node update layer2: norm + residual + LN + head ----------------
__global__ __launch_bounds__(256) void k_node2(
    const float* __restrict__ S, const float* __restrict__ dsum,
    const float* __restrict__ h2, const float* __restrict__ g,
    const float* __restrict__ be, const float* __restrict__ rW,
    const float* __restrict__ rb, float* __restrict__ out, int N)
{
    int n = blockIdx.x * blockDim.x + threadIdx.x;
    if (n >= N) return;
    float dn = dsum[n] + 1e-8f;
    float v[4];
#pragma unroll
    for (int k = 0; k < 4; ++k) v[k] = S[n * 4 + k] / dn + h2[n * 4 + k];
    float mu = 0.25f * (v[0] + v[1] + v[2] + v[3]);
    float var = 0.f;
#pragma unroll
    for (int k = 0; k < 4; ++k) { float t = v[k] - mu; var += t * t; }
    var *= 0.25f;
    float rs = 1.0f / sqrtf(var + 1e-5f);
    float acc = rb[0];
#pragma unroll
    for (int k = 0; k < 4; ++k) acc += ((v[k] - mu) * rs * g[k] + be[k]) * rW[k];
    out[n] = acc;
}

extern "C" void kernel_launch(void* const* d_in, const int* in_sizes, int n_in,
                              void* d_out, int out_size, void* d_ws, size_t ws_size,
                              hipStream_t stream)
{
    const float* x    = (const float*)d_in[0];
    const int*   ei   = (const int*)d_in[1];
    const float* ea   = (const float*)d_in[2];
    const float* W_ih = (const float*)d_in[3];
    const float* W_hh = (const float*)d_in[4];
    const float* b_ih = (const float*)d_in[5];
    const float* b_hh = (const float*)d_in[6];
    const float* p1W  = (const float*)d_in[7];
    const float* p1b  = (const float*)d_in[8];
    const float* a1W  = (const float*)d_in[9];
    const float* q1w  = (const float*)d_in[10];
    const float* g1   = (const float*)d_in[11];
    const float* be1  = (const float*)d_in[12];
    const float* p2W  = (const float*)d_in[13];
    const float* p2b  = (const float*)d_in[14];
    const float* a2W  = (const float*)d_in[15];
    const float* q2w  = (const float*)d_in[16];
    const float* g2   = (const float*)d_in[17];
    const float* be2  = (const float*)d_in[18];
    const float* rW   = (const float*)d_in[19];
    const float* rb   = (const float*)d_in[20];
    float* out = (float*)d_out;

    int N  = in_sizes[0] / 13;
    int E  = in_sizes[1] / 2;
    int EN = E + N;

    // workspace layout (floats)
    float* ws    = (float*)d_ws;
    float* h1    = ws;                       // N*4
    float* h2    = h1 + (size_t)N * 4;       // N*4
    float* alpha = h2 + (size_t)N * 4;       // EN
    float* S1    = alpha + (size_t)EN;       // N*4
    float* d1    = S1 + (size_t)N * 4;       // N
    float* S2    = d1 + (size_t)N;           // N*4
    float* d2    = S2 + (size_t)N * 4;       // N
    unsigned* gm = (unsigned*)(d2 + (size_t)N); // 2 slots

    size_t zbytes = (size_t)((char*)(gm + 2) - (char*)S1);
    hipMemsetAsync(S1, 0, zbytes, stream);  // zero accumulators + max slots

    const int B = 256;
    k_gru<<<(N + B - 1) / B, B, 0, stream>>>(x, W_ih, W_hh, b_ih, b_hh, p1W, p1b, h1, N);

    k_alpha<<<(EN + B - 1) / B, B, 0, stream>>>(ei, ea, h1, a1W, alpha, gm + 0, E, N);
    k_msg<<<(EN + B - 1) / B, B, 0, stream>>>(ei, ea, h1, alpha, gm + 0, q1w, S1, d1, E, N);
    k_node1<<<(N + B - 1) / B, B, 0, stream>>>(S1, d1, h1, g1, be1, p2W, p2b, h2, N);

    k_alpha<<<(EN + B - 1) / B, B, 0, stream>>>(ei, ea, h2, a2W, alpha, gm + 1, E, N);
    k_msg<<<(EN + B - 1) / B, B, 0, stream>>>(ei, ea, h2, alpha, gm + 1, q2w, S2, d2, E, N);
    k_node2<<<(N + B - 1) / B, B, 0, stream>>>(S2, d2, h2, g2, be2, rW, rb, out, N);
}

// Round 2
// 442.240 us; speedup vs baseline: 1.7236x; 1.7236x over previous
//
#include <hip/hip_runtime.h>
#include <math.h>

// QTGNN: GRU(10 steps, hidden16) -> QGAT layer1 -> QGAT layer2 -> linear head.
// N=10000 nodes, E=320000 edges (+N self loops). All fp32.
// R1: GRU restructured to 16 threads/node (shfl-broadcast matvec) after R0
//     profile showed 256 VGPR + 30MB scratch spill traffic + 1.7% occupancy.
//     Uniform weight-gate angles + per-node input angles precomputed.

#define GH 16
#define SEQ 10
#define PI_F 3.14159265358979323846f

__device__ __forceinline__ float sigmoidf_(float x) { return 1.0f / (1.0f + expf(-x)); }

// monotonic float<->uint mapping for atomicMax on signed floats
__device__ __forceinline__ unsigned fkey(float f) {
    unsigned u = __float_as_uint(f);
    return (u & 0x80000000u) ? ~u : (u | 0x80000000u);
}
__device__ __forceinline__ float funkey(unsigned k) {
    return __uint_as_float((k & 0x80000000u) ? (k ^ 0x80000000u) : ~k);
}

// ---------------- GRU (16 threads/node) + layer-1 ELU projection + angle precompute ----------------
// grid: N/16 blocks of 256 threads; thread = (node-in-block, hidden unit j)
__global__ __launch_bounds__(256) void k_gru(
    const float* __restrict__ x, const float* __restrict__ W_ih,
    const float* __restrict__ W_hh, const float* __restrict__ b_ih,
    const float* __restrict__ b_hh, const float* __restrict__ p1W,
    const float* __restrict__ p1b, const float* __restrict__ q1w,
    const float* __restrict__ q2w, float* __restrict__ h1,
    float* __restrict__ cs1, float* __restrict__ qcs, int N)
{
    __shared__ float sW[48 * 16];
    __shared__ float sp1W[4 * 19], sp1b[4];
    for (int i = threadIdx.x; i < 48 * 16; i += 256) sW[i] = W_hh[i];
    if (threadIdx.x < 76) sp1W[threadIdx.x] = p1W[threadIdx.x];
    if (threadIdx.x < 4) sp1b[threadIdx.x] = p1b[threadIdx.x];
    __syncthreads();

    // uniform weight-gate angle table (both layers), once on block 0
    if (blockIdx.x == 0 && threadIdx.x < 12) {
        const float* qw = (threadIdx.x < 6) ? q1w : q2w;
        int rd = threadIdx.x % 6;
        float sy, cy; sincosf(0.5f * qw[rd * 2 + 0], &sy, &cy);
        float sz, cz; sincosf(0.5f * qw[rd * 2 + 1], &sz, &cz);
        float* q = qcs + threadIdx.x * 4;
        q[0] = cy; q[1] = sy; q[2] = cz; q[3] = sz;
    }

    const int j = threadIdx.x & 15;          // hidden unit
    const int n = blockIdx.x * 16 + (threadIdx.x >> 4);
    const bool valid = (n < N);

    // W_hh rows j, 16+j, 32+j in registers
    float wr[GH], wz[GH], wn[GH];
#pragma unroll
    for (int k = 0; k < GH; ++k) {
        wr[k] = sW[j * 16 + k];
        wz[k] = sW[(16 + j) * 16 + k];
        wn[k] = sW[(32 + j) * 16 + k];
    }
    float wir = W_ih[j], wiz = W_ih[16 + j], win_ = W_ih[32 + j];
    float bir = b_ih[j], biz = b_ih[16 + j], bin_ = b_ih[32 + j];
    float brr = b_hh[j], brz = b_hh[16 + j], brn = b_hh[32 + j];

    float xv[13];
#pragma unroll
    for (int t = 0; t < 13; ++t) xv[t] = valid ? x[n * 13 + t] : 0.f;

    float h = 0.f;
#pragma unroll
    for (int t = 0; t < SEQ; ++t) {
        float xt = xv[t];
        float ghr = brr, ghz = brz, ghn = brn;
#pragma unroll
        for (int k = 0; k < GH; ++k) {
            float hk = __shfl(h, k, 16);
            ghr += wr[k] * hk; ghz += wz[k] * hk; ghn += wn[k] * hk;
        }
        float r  = sigmoidf_(xt * wir + bir + ghr);
        float z  = sigmoidf_(xt * wiz + biz + ghz);
        float nv = tanhf(xt * win_ + bin_ + r * ghn);
        h = (1.f - z) * nv + z * h;
    }

    // proj1: elu([h, x[10:13]] @ p1W.T + p1b) via 16-lane butterfly
    float s0 = h * sp1W[0 * 19 + j];
    float s1 = h * sp1W[1 * 19 + j];
    float s2 = h * sp1W[2 * 19 + j];
    float s3 = h * sp1W[3 * 19 + j];
#pragma unroll
    for (int m = 1; m < 16; m <<= 1) {
        s0 += __shfl_xor(s0, m, 16);
        s1 += __shfl_xor(s1, m, 16);
        s2 += __shfl_xor(s2, m, 16);
        s3 += __shfl_xor(s3, m, 16);
    }
    if (valid && j < 4) {
        float s = (j == 0) ? s0 : (j == 1) ? s1 : (j == 2) ? s2 : s3;
        s += sp1b[j] + xv[10] * sp1W[j * 19 + 16] + xv[11] * sp1W[j * 19 + 17]
           + xv[12] * sp1W[j * 19 + 18];
        float hv = (s > 0.f) ? s : expm1f(s);
        h1[n * 4 + j] = hv;
        float sv, cv; sincosf(0.5f * PI_F * tanhf(hv), &sv, &cv);
        cs1[n * 8 + 2 * j]     = cv;
        cs1[n * 8 + 2 * j + 1] = sv;
    }
}

// ---------------- attention logits + global max ----------------
__global__ __launch_bounds__(256) void k_alpha(
    const int* __restrict__ ei, const float* __restrict__ ea,
    const float* __restrict__ h, const float* __restrict__ Wa,
    float* __restrict__ alpha, unsigned* __restrict__ gmax, int E, int N)
{
    int e = blockIdx.x * blockDim.x + threadIdx.x;
    int EN = E + N;
    float a = -INFINITY;
    if (e < EN) {
        int src = (e < E) ? ei[e] : (e - E);
        int dst = (e < E) ? ei[E + e] : (e - E);
        float eav = (e < E) ? ea[e] : 1.0f;
        float s0 = 0.f;
#pragma unroll
        for (int k = 0; k < 4; ++k) s0 += h[src * 4 + k] * Wa[k] + h[dst * 4 + k] * Wa[4 + k];
        s0 = (s0 > 0.f) ? s0 : 0.2f * s0;
        a = s0 * fabsf(eav);
        alpha[e] = a;
    }
    float m = a;
#pragma unroll
    for (int off = 32; off; off >>= 1) m = fmaxf(m, __shfl_down(m, off));
    if ((threadIdx.x & 63) == 0) atomicMax(gmax, fkey(m));
}

// ---------------- quantum gate helpers (all indices compile-time) ----------------
template <int STR>
__device__ __forceinline__ void ry_g(float (&sr)[16], float (&si)[16], float c, float s) {
#pragma unroll
    for (int i0 = 0; i0 < 16; ++i0) {
        if (i0 & STR) continue;
        int i1 = i0 | STR;
        float a0r = sr[i0], a0i = si[i0], a1r = sr[i1], a1i = si[i1];
        sr[i0] = c * a0r - s * a1r; si[i0] = c * a0i - s * a1i;
        sr[i1] = s * a0r + c * a1r; si[i1] = s * a0i + c * a1i;
    }
}
template <int STR>
__device__ __forceinline__ void rz_g(float (&sr)[16], float (&si)[16], float c, float s) {
#pragma unroll
    for (int i = 0; i < 16; ++i) {
        float r = sr[i], im = si[i];
        if (i & STR) { sr[i] = r * c - im * s; si[i] = im * c + r * s; }
        else         { sr[i] = r * c + im * s; si[i] = im * c - r * s; }
    }
}
template <int SC, int ST>
__device__ __forceinline__ void cnot_g(float (&sr)[16], float (&si)[16]) {
#pragma unroll
    for (int i = 0; i < 16; ++i) {
        if ((i & SC) && !(i & ST)) {
            int j = i | ST;
            float tr = sr[i], ti = si[i];
            sr[i] = sr[j]; si[i] = si[j]; sr[j] = tr; si[j] = ti;
        }
    }
}

// ---------------- per-edge message: softmax-numerator x qcircuit, atomic aggregate ----------------
__global__ __launch_bounds__(256) void k_msg(
    const int* __restrict__ ei, const float* __restrict__ ea,
    const float* __restrict__ cs, const float* __restrict__ alpha,
    const unsigned* __restrict__ gmax, const float* __restrict__ qcsL,
    float* __restrict__ S, float* __restrict__ dsum, int E, int N)
{
    int e = blockIdx.x * blockDim.x + threadIdx.x;
    int EN = E + N;
    if (e >= EN) return;
    int src = (e < E) ? ei[e] : (e - E);
    int dst = (e < E) ? ei[E + e] : (e - E);
    float eav = (e < E) ? ea[e] : 1.0f;

    float gm = funkey(*gmax);
    float aexp = expf(alpha[e] - gm);

    // precomputed per-node input-gate angles (cos/sin pairs)
    float ic[5], is_[5];
    float4 c01 = *reinterpret_cast<const float4*>(&cs[src * 8]);
    float4 c23 = *reinterpret_cast<const float4*>(&cs[src * 8 + 4]);
    ic[0] = c01.x; is_[0] = c01.y; ic[1] = c01.z; is_[1] = c01.w;
    ic[2] = c23.x; is_[2] = c23.y; ic[3] = c23.z; is_[3] = c23.w;
    {
        float sv, cv; sincosf(0.5f * PI_F * tanhf(eav), &sv, &cv);
        ic[4] = cv; is_[4] = sv;
    }
    // uniform weight-gate angles (precomputed)
    float wyc[6], wys[6], wzc[6], wzs[6];
#pragma unroll
    for (int rd = 0; rd < 6; ++rd) {
        wyc[rd] = qcsL[rd * 4 + 0]; wys[rd] = qcsL[rd * 4 + 1];
        wzc[rd] = qcsL[rd * 4 + 2]; wzs[rd] = qcsL[rd * 4 + 3];
    }

    float sr[16], si[16];
#pragma unroll
    for (int i = 0; i < 16; ++i) { sr[i] = 0.f; si[i] = 0.f; }
    sr[0] = 1.f;

#pragma unroll
    for (int r = 0; r < 3; ++r) {
        ry_g<8>(sr, si, ic[0], is_[0]);
        ry_g<4>(sr, si, ic[1], is_[1]);
        ry_g<2>(sr, si, ic[2], is_[2]);
        ry_g<1>(sr, si, ic[3], is_[3]);
        ry_g<8>(sr, si, ic[4], is_[4]);
#pragma unroll
        for (int d = 0; d < 2; ++d) {
            int rd = r * 2 + d;
            float cy = wyc[rd], sy = wys[rd], cz = wzc[rd], sz = wzs[rd];
            ry_g<8>(sr, si, cy, sy); rz_g<8>(sr, si, cz, sz);
            ry_g<4>(sr, si, cy, sy); rz_g<4>(sr, si, cz, sz);
            ry_g<2>(sr, si, cy, sy); rz_g<2>(sr, si, cz, sz);
            ry_g<1>(sr, si, cy, sy); rz_g<1>(sr, si, cz, sz);
            if (d == 0) { cnot_g<8, 4>(sr, si); cnot_g<2, 1>(sr, si); }
            else        { cnot_g<4, 2>(sr, si); }
        }
    }

    float p[16];
#pragma unroll
    for (int i = 0; i < 16; ++i) p[i] = sr[i] * sr[i] + si[i] * si[i];
#pragma unroll
    for (int w = 0; w < 4; ++w) {
        const int STR = 8 >> w;
        float z = 0.f;
#pragma unroll
        for (int i = 0; i < 16; ++i) z += (i & STR) ? -p[i] : p[i];
        atomicAdd(&S[dst * 4 + w], aexp * z);
    }
    atomicAdd(&dsum[dst], aexp);
}

// ---------------- node update layer1: norm + residual + LN + relu + proj2 + angles ----------------
__global__ __launch_bounds__(256) void k_node1(
    const float* __restrict__ S, const float* __restrict__ dsum,
    const float* __restrict__ h1, const float* __restrict__ g,
    const float* __restrict__ be, const float* __restrict__ p2W,
    const float* __restrict__ p2b, float* __restrict__ h2,
    float* __restrict__ cs2, int N)
{
    int n = blockIdx.x * blockDim.x + threadIdx.x;
    if (n >= N) return;
    float dn = dsum[n] + 1e-8f;
    float v[4];
#pragma unroll
    for (int k = 0; k < 4; ++k) v[k] = S[n * 4 + k] / dn + h1[n * 4 + k];
    float mu = 0.25f * (v[0] + v[1] + v[2] + v[3]);
    float var = 0.f;
#pragma unroll
    for (int k = 0; k < 4; ++k) { float t = v[k] - mu; var += t * t; }
    var *= 0.25f;
    float rs = 1.0f / sqrtf(var + 1e-5f);
    float y[4];
#pragma unroll
    for (int k = 0; k < 4; ++k) {
        float t = (v[k] - mu) * rs * g[k] + be[k];
        y[k] = fmaxf(t, 0.f);  // relu between layers
    }
#pragma unroll
    for (int w = 0; w < 4; ++w) {
        float s = p2b[w];
#pragma unroll
        for (int k = 0; k < 4; ++k) s += y[k] * p2W[w * 4 + k];
        float hv = (s > 0.f) ? s : expm1f(s);
        h2[n * 4 + w] = hv;
        float sv, cv; sincosf(0.5f * PI_F * tanhf(hv), &sv, &cv);
        cs2[n * 8 + 2 * w]     = cv;
        cs2[n * 8 + 2 * w + 1] = sv;
    }
}

// ---------------- node update layer2: norm + residual + LN + head ----------------
__global__ __launch_bounds__(256) void k_node2(
    const float* __restrict__ S, const float* __restrict__ dsum,
    const float* __restrict__ h2, const float* __restrict__ g,
    const float* __restrict__ be, const float* __restrict__ rW,
    const float* __restrict__ rb, float* __restrict__ out, int N)
{
    int n = blockIdx.x * blockDim.x + threadIdx.x;
    if (n >= N) return;
    float dn = dsum[n] + 1e-8f;
    float v[4];
#pragma unroll
    for (int k = 0; k < 4; ++k) v[k] = S[n * 4 + k] / dn + h2[n * 4 + k];
    float mu = 0.25f * (v[0] + v[1] + v[2] + v[3]);
    float var = 0.f;
#pragma unroll
    for (int k = 0; k < 4; ++k) { float t = v[k] - mu; var += t * t; }
    var *= 0.25f;
    float rs = 1.0f / sqrtf(var + 1e-5f);
    float acc = rb[0];
#pragma unroll
    for (int k = 0; k < 4; ++k) acc += ((v[k] - mu) * rs * g[k] + be[k]) * rW[k];
    out[n] = acc;
}

extern "C" void kernel_launch(void* const* d_in, const int* in_sizes, int n_in,
                              void* d_out, int out_size, void* d_ws, size_t ws_size,
                              hipStream_t stream)
{
    const float* x    = (const float*)d_in[0];
    const int*   ei   = (const int*)d_in[1];
    const float* ea   = (const float*)d_in[2];
    const float* W_ih = (const float*)d_in[3];
    const float* W_hh = (const float*)d_in[4];
    const float* b_ih = (const float*)d_in[5];
    const float* b_hh = (const float*)d_in[6];
    const float* p1W  = (const float*)d_in[7];
    const float* p1b  = (const float*)d_in[8];
    const float* a1W  = (const float*)d_in[9];
    const float* q1w  = (const float*)d_in[10];
    const float* g1   = (const float*)d_in[11];
    const float* be1  = (const float*)d_in[12];
    const float* p2W  = (const float*)d_in[13];
    const float* p2b  = (const float*)d_in[14];
    const float* a2W  = (const float*)d_in[15];
    const float* q2w  = (const float*)d_in[16];
    const float* g2   = (const float*)d_in[17];
    const float* be2  = (const float*)d_in[18];
    const float* rW   = (const float*)d_in[19];
    const float* rb   = (const float*)d_in[20];
    float* out = (float*)d_out;

    int N  = in_sizes[0] / 13;
    int E  = in_sizes[1] / 2;
    int EN = E + N;

    // workspace layout (floats, all 16B-aligned partitions)
    float* ws    = (float*)d_ws;
    float* h1    = ws;                        // N*4
    float* h2    = h1 + (size_t)N * 4;        // N*4
    float* cs1   = h2 + (size_t)N * 4;        // N*8
    float* cs2   = cs1 + (size_t)N * 8;       // N*8
    float* alpha = cs2 + (size_t)N * 8;       // EN
    float* S1    = alpha + (size_t)EN;        // N*4   (zeroed)
    float* d1    = S1 + (size_t)N * 4;        // N     (zeroed)
    float* S2    = d1 + (size_t)N;            // N*4   (zeroed)
    float* d2    = S2 + (size_t)N * 4;        // N     (zeroed)
    float* qcs   = d2 + (size_t)N;            // 48
    unsigned* gm = (unsigned*)(qcs + 48);     // 2 slots (zeroed)

    size_t zbytes = (size_t)((char*)(gm + 2) - (char*)S1);
    hipMemsetAsync(S1, 0, zbytes, stream);  // zero accumulators + max slots

    const int B = 256;
    k_gru<<<(N + 15) / 16, B, 0, stream>>>(x, W_ih, W_hh, b_ih, b_hh, p1W, p1b,
                                           q1w, q2w, h1, cs1, qcs, N);

    k_alpha<<<(EN + B - 1) / B, B, 0, stream>>>(ei, ea, h1, a1W, alpha, gm + 0, E, N);
    k_msg<<<(EN + B - 1) / B, B, 0, stream>>>(ei, ea, cs1, alpha, gm + 0, qcs, S1, d1, E, N);
    k_node1<<<(N + B - 1) / B, B, 0, stream>>>(S1, d1, h1, g1, be1, p2W, p2b, h2, cs2, N);

    k_alpha<<<(EN + B - 1) / B, B, 0, stream>>>(ei, ea, h2, a2W, alpha, gm + 1, E, N);
    k_msg<<<(EN + B - 1) / B, B, 0, stream>>>(ei, ea, cs2, alpha, gm + 1, qcs + 24, S2, d2, E, N);
    k_node2<<<(N + B - 1) / B, B, 0, stream>>>(S2, d2, h2, g2, be2, rW, rb, out, N);
}

// Round 3
// 302.986 us; speedup vs baseline: 2.5157x; 1.4596x over previous
//
#include <hip/hip_runtime.h>
#include <math.h>

// QTGNN: GRU(10 steps, hidden16) -> QGAT layer1 -> QGAT layer2 -> linear head.
// N=10000 nodes, E=320000 edges (+N self loops). All fp32.
// R1: GRU 16 threads/node (shfl matvec) — fixed 256-VGPR spill + 1.7% occupancy.
// R2: k_msg atomics were cross-XCD thrashing (50MB WRITE_SIZE for a 200KB
//     accumulator). Fix: per-XCD accumulator replicas (blockIdx&7 ~ XCD id,
//     round-robin dispatch), reduced in the node kernels. Also: softmax is
//     shift-invariant up to the 1e-8 eps -> drop the global-max pass and fuse
//     the attention logit into the message kernel (saves 2 launches + alpha
//     buffer round-trip + gmax atomic hotspot).

#define GH 16
#define SEQ 10
#define PI_F 3.14159265358979323846f

__device__ __forceinline__ float sigmoidf_(float x) { return 1.0f / (1.0f + expf(-x)); }

// ---------------- GRU (16 threads/node) + layer-1 ELU projection + angle precompute ----------------
__global__ __launch_bounds__(256) void k_gru(
    const float* __restrict__ x, const float* __restrict__ W_ih,
    const float* __restrict__ W_hh, const float* __restrict__ b_ih,
    const float* __restrict__ b_hh, const float* __restrict__ p1W,
    const float* __restrict__ p1b, const float* __restrict__ q1w,
    const float* __restrict__ q2w, float* __restrict__ h1,
    float* __restrict__ cs1, float* __restrict__ qcs, int N)
{
    __shared__ float sW[48 * 16];
    __shared__ float sp1W[4 * 19], sp1b[4];
    for (int i = threadIdx.x; i < 48 * 16; i += 256) sW[i] = W_hh[i];
    if (threadIdx.x < 76) sp1W[threadIdx.x] = p1W[threadIdx.x];
    if (threadIdx.x < 4) sp1b[threadIdx.x] = p1b[threadIdx.x];
    __syncthreads();

    // uniform weight-gate angle table (both layers), once on block 0
    if (blockIdx.x == 0 && threadIdx.x < 12) {
        const float* qw = (threadIdx.x < 6) ? q1w : q2w;
        int rd = threadIdx.x % 6;
        float sy, cy; sincosf(0.5f * qw[rd * 2 + 0], &sy, &cy);
        float sz, cz; sincosf(0.5f * qw[rd * 2 + 1], &sz, &cz);
        float* q = qcs + threadIdx.x * 4;
        q[0] = cy; q[1] = sy; q[2] = cz; q[3] = sz;
    }

    const int j = threadIdx.x & 15;          // hidden unit
    const int n = blockIdx.x * 16 + (threadIdx.x >> 4);
    const bool valid = (n < N);

    float wr[GH], wz[GH], wn[GH];
#pragma unroll
    for (int k = 0; k < GH; ++k) {
        wr[k] = sW[j * 16 + k];
        wz[k] = sW[(16 + j) * 16 + k];
        wn[k] = sW[(32 + j) * 16 + k];
    }
    float wir = W_ih[j], wiz = W_ih[16 + j], win_ = W_ih[32 + j];
    float bir = b_ih[j], biz = b_ih[16 + j], bin_ = b_ih[32 + j];
    float brr = b_hh[j], brz = b_hh[16 + j], brn = b_hh[32 + j];

    float xv[13];
#pragma unroll
    for (int t = 0; t < 13; ++t) xv[t] = valid ? x[n * 13 + t] : 0.f;

    float h = 0.f;
#pragma unroll
    for (int t = 0; t < SEQ; ++t) {
        float xt = xv[t];
        float ghr = brr, ghz = brz, ghn = brn;
#pragma unroll
        for (int k = 0; k < GH; ++k) {
            float hk = __shfl(h, k, 16);
            ghr += wr[k] * hk; ghz += wz[k] * hk; ghn += wn[k] * hk;
        }
        float r  = sigmoidf_(xt * wir + bir + ghr);
        float z  = sigmoidf_(xt * wiz + biz + ghz);
        float nv = tanhf(xt * win_ + bin_ + r * ghn);
        h = (1.f - z) * nv + z * h;
    }

    // proj1: elu([h, x[10:13]] @ p1W.T + p1b) via 16-lane butterfly
    float s0 = h * sp1W[0 * 19 + j];
    float s1 = h * sp1W[1 * 19 + j];
    float s2 = h * sp1W[2 * 19 + j];
    float s3 = h * sp1W[3 * 19 + j];
#pragma unroll
    for (int m = 1; m < 16; m <<= 1) {
        s0 += __shfl_xor(s0, m, 16);
        s1 += __shfl_xor(s1, m, 16);
        s2 += __shfl_xor(s2, m, 16);
        s3 += __shfl_xor(s3, m, 16);
    }
    if (valid && j < 4) {
        float s = (j == 0) ? s0 : (j == 1) ? s1 : (j == 2) ? s2 : s3;
        s += sp1b[j] + xv[10] * sp1W[j * 19 + 16] + xv[11] * sp1W[j * 19 + 17]
           + xv[12] * sp1W[j * 19 + 18];
        float hv = (s > 0.f) ? s : expm1f(s);
        h1[n * 4 + j] = hv;
        float sv, cv; sincosf(0.5f * PI_F * tanhf(hv), &sv, &cv);
        cs1[n * 8 + 2 * j]     = cv;
        cs1[n * 8 + 2 * j + 1] = sv;
    }
}

// ---------------- quantum gate helpers (all indices compile-time) ----------------
template <int STR>
__device__ __forceinline__ void ry_g(float (&sr)[16], float (&si)[16], float c, float s) {
#pragma unroll
    for (int i0 = 0; i0 < 16; ++i0) {
        if (i0 & STR) continue;
        int i1 = i0 | STR;
        float a0r = sr[i0], a0i = si[i0], a1r = sr[i1], a1i = si[i1];
        sr[i0] = c * a0r - s * a1r; si[i0] = c * a0i - s * a1i;
        sr[i1] = s * a0r + c * a1r; si[i1] = s * a0i + c * a1i;
    }
}
template <int STR>
__device__ __forceinline__ void rz_g(float (&sr)[16], float (&si)[16], float c, float s) {
#pragma unroll
    for (int i = 0; i < 16; ++i) {
        float r = sr[i], im = si[i];
        if (i & STR) { sr[i] = r * c - im * s; si[i] = im * c + r * s; }
        else         { sr[i] = r * c + im * s; si[i] = im * c - r * s; }
    }
}
template <int SC, int ST>
__device__ __forceinline__ void cnot_g(float (&sr)[16], float (&si)[16]) {
#pragma unroll
    for (int i = 0; i < 16; ++i) {
        if ((i & SC) && !(i & ST)) {
            int j = i | ST;
            float tr = sr[i], ti = si[i];
            sr[i] = sr[j]; si[i] = si[j]; sr[j] = tr; si[j] = ti;
        }
    }
}

// ---------------- fused per-edge: attention + qcircuit + XCD-replica atomic aggregate ----------------
__global__ __launch_bounds__(256) void k_msgf(
    const int* __restrict__ ei, const float* __restrict__ ea,
    const float* __restrict__ h, const float* __restrict__ cs,
    const float* __restrict__ Wa, const float* __restrict__ qcsL,
    float* __restrict__ RS, int rmask, int E, int N)
{
    int e = blockIdx.x * 256 + threadIdx.x;
    int EN = E + N;
    if (e >= EN) return;
    int src = (e < E) ? ei[e] : (e - E);
    int dst = (e < E) ? ei[E + e] : (e - E);
    float eav = (e < E) ? ea[e] : 1.0f;
    float aea = fabsf(eav);

    // attention logit -> unnormalized softmax weight (no max shift; see header)
    float4 hs = *reinterpret_cast<const float4*>(&h[src * 4]);
    float4 hd = *reinterpret_cast<const float4*>(&h[dst * 4]);
    float s0 = hs.x * Wa[0] + hs.y * Wa[1] + hs.z * Wa[2] + hs.w * Wa[3]
             + hd.x * Wa[4] + hd.y * Wa[5] + hd.z * Wa[6] + hd.w * Wa[7];
    s0 = (s0 > 0.f) ? s0 : 0.2f * s0;
    float aexp = expf(s0 * aea);

    // precomputed per-node input-gate angles + per-edge corr angle
    float ic[5], is_[5];
    float4 c01 = *reinterpret_cast<const float4*>(&cs[src * 8]);
    float4 c23 = *reinterpret_cast<const float4*>(&cs[src * 8 + 4]);
    ic[0] = c01.x; is_[0] = c01.y; ic[1] = c01.z; is_[1] = c01.w;
    ic[2] = c23.x; is_[2] = c23.y; ic[3] = c23.z; is_[3] = c23.w;
    {
        float sv, cv; sincosf(0.5f * PI_F * tanhf(eav), &sv, &cv);
        ic[4] = cv; is_[4] = sv;
    }
    float wyc[6], wys[6], wzc[6], wzs[6];
#pragma unroll
    for (int rd = 0; rd < 6; ++rd) {
        wyc[rd] = qcsL[rd * 4 + 0]; wys[rd] = qcsL[rd * 4 + 1];
        wzc[rd] = qcsL[rd * 4 + 2]; wzs[rd] = qcsL[rd * 4 + 3];
    }

    float sr[16], si[16];
#pragma unroll
    for (int i = 0; i < 16; ++i) { sr[i] = 0.f; si[i] = 0.f; }
    sr[0] = 1.f;

#pragma unroll
    for (int r = 0; r < 3; ++r) {
        ry_g<8>(sr, si, ic[0], is_[0]);
        ry_g<4>(sr, si, ic[1], is_[1]);
        ry_g<2>(sr, si, ic[2], is_[2]);
        ry_g<1>(sr, si, ic[3], is_[3]);
        ry_g<8>(sr, si, ic[4], is_[4]);
#pragma unroll
        for (int d = 0; d < 2; ++d) {
            int rd = r * 2 + d;
            float cy = wyc[rd], sy = wys[rd], cz = wzc[rd], sz = wzs[rd];
            ry_g<8>(sr, si, cy, sy); rz_g<8>(sr, si, cz, sz);
            ry_g<4>(sr, si, cy, sy); rz_g<4>(sr, si, cz, sz);
            ry_g<2>(sr, si, cy, sy); rz_g<2>(sr, si, cz, sz);
            ry_g<1>(sr, si, cy, sy); rz_g<1>(sr, si, cz, sz);
            if (d == 0) { cnot_g<8, 4>(sr, si); cnot_g<2, 1>(sr, si); }
            else        { cnot_g<4, 2>(sr, si); }
        }
    }

    float p[16];
#pragma unroll
    for (int i = 0; i < 16; ++i) p[i] = sr[i] * sr[i] + si[i] * si[i];

    // replica for this block's XCD (blockIdx round-robins across 8 XCDs)
    float* rbase = RS + (size_t)(blockIdx.x & rmask) * (size_t)N * 5 + (size_t)dst * 5;
#pragma unroll
    for (int w = 0; w < 4; ++w) {
        const int STR = 8 >> w;
        float z = 0.f;
#pragma unroll
        for (int i = 0; i < 16; ++i) z += (i & STR) ? -p[i] : p[i];
        atomicAdd(rbase + w, aexp * z);
    }
    atomicAdd(rbase + 4, aexp);
}

// ---------------- node update layer1: replica-reduce + norm + residual + LN + relu + proj2 + angles ----------------
__global__ __launch_bounds__(256) void k_node1(
    const float* __restrict__ RS, int nrep,
    const float* __restrict__ h1, const float* __restrict__ g,
    const float* __restrict__ be, const float* __restrict__ p2W,
    const float* __restrict__ p2b, float* __restrict__ h2,
    float* __restrict__ cs2, int N)
{
    int n = blockIdx.x * blockDim.x + threadIdx.x;
    if (n >= N) return;
    float sa[4] = {0.f, 0.f, 0.f, 0.f};
    float dn = 1e-8f;
    for (int r = 0; r < nrep; ++r) {
        const float* b = RS + ((size_t)r * N + n) * 5;
        sa[0] += b[0]; sa[1] += b[1]; sa[2] += b[2]; sa[3] += b[3]; dn += b[4];
    }
    float v[4];
#pragma unroll
    for (int k = 0; k < 4; ++k) v[k] = sa[k] / dn + h1[n * 4 + k];
    float mu = 0.25f * (v[0] + v[1] + v[2] + v[3]);
    float var = 0.f;
#pragma unroll
    for (int k = 0; k < 4; ++k) { float t = v[k] - mu; var += t * t; }
    var *= 0.25f;
    float rs = 1.0f / sqrtf(var + 1e-5f);
    float y[4];
#pragma unroll
    for (int k = 0; k < 4; ++k) {
        float t = (v[k] - mu) * rs * g[k] + be[k];
        y[k] = fmaxf(t, 0.f);  // relu between layers
    }
#pragma unroll
    for (int w = 0; w < 4; ++w) {
        float s = p2b[w];
#pragma unroll
        for (int k = 0; k < 4; ++k) s += y[k] * p2W[w * 4 + k];
        float hv = (s > 0.f) ? s : expm1f(s);
        h2[n * 4 + w] = hv;
        float sv, cv; sincosf(0.5f * PI_F * tanhf(hv), &sv, &cv);
        cs2[n * 8 + 2 * w]     = cv;
        cs2[n * 8 + 2 * w + 1] = sv;
    }
}

// ---------------- node update layer2: replica-reduce + norm + residual + LN + head ----------------
__global__ __launch_bounds__(256) void k_node2(
    const float* __restrict__ RS, int nrep,
    const float* __restrict__ h2, const float* __restrict__ g,
    const float* __restrict__ be, const float* __restrict__ rW,
    const float* __restrict__ rb, float* __restrict__ out, int N)
{
    int n = blockIdx.x * blockDim.x + threadIdx.x;
    if (n >= N) return;
    float sa[4] = {0.f, 0.f, 0.f, 0.f};
    float dn = 1e-8f;
    for (int r = 0; r < nrep; ++r) {
        const float* b = RS + ((size_t)r * N + n) * 5;
        sa[0] += b[0]; sa[1] += b[1]; sa[2] += b[2]; sa[3] += b[3]; dn += b[4];
    }
    float v[4];
#pragma unroll
    for (int k = 0; k < 4; ++k) v[k] = sa[k] / dn + h2[n * 4 + k];
    float mu = 0.25f * (v[0] + v[1] + v[2] + v[3]);
    float var = 0.f;
#pragma unroll
    for (int k = 0; k < 4; ++k) { float t = v[k] - mu; var += t * t; }
    var *= 0.25f;
    float rs = 1.0f / sqrtf(var + 1e-5f);
    float acc = rb[0];
#pragma unroll
    for (int k = 0; k < 4; ++k) acc += ((v[k] - mu) * rs * g[k] + be[k]) * rW[k];
    out[n] = acc;
}

extern "C" void kernel_launch(void* const* d_in, const int* in_sizes, int n_in,
                              void* d_out, int out_size, void* d_ws, size_t ws_size,
                              hipStream_t stream)
{
    const float* x    = (const float*)d_in[0];
    const int*   ei   = (const int*)d_in[1];
    const float* ea   = (const float*)d_in[2];
    const float* W_ih = (const float*)d_in[3];
    const float* W_hh = (const float*)d_in[4];
    const float* b_ih = (const float*)d_in[5];
    const float* b_hh = (const float*)d_in[6];
    const float* p1W  = (const float*)d_in[7];
    const float* p1b  = (const float*)d_in[8];
    const float* a1W  = (const float*)d_in[9];
    const float* q1w  = (const float*)d_in[10];
    const float* g1   = (const float*)d_in[11];
    const float* be1  = (const float*)d_in[12];
    const float* p2W  = (const float*)d_in[13];
    const float* p2b  = (const float*)d_in[14];
    const float* a2W  = (const float*)d_in[15];
    const float* q2w  = (const float*)d_in[16];
    const float* g2   = (const float*)d_in[17];
    const float* be2  = (const float*)d_in[18];
    const float* rW   = (const float*)d_in[19];
    const float* rb   = (const float*)d_in[20];
    float* out = (float*)d_out;

    int N  = in_sizes[0] / 13;
    int E  = in_sizes[1] / 2;
    int EN = E + N;

    // pick replica count (power of 2, <=8) that fits ws
    size_t base_f = (size_t)N * 4 * 2 + (size_t)N * 8 * 2 + 64;  // h1,h2,cs1,cs2,qcs(pad)
    int nrep = 8;
    while (nrep > 1 && (base_f + 2 * (size_t)nrep * N * 5) * 4 > ws_size) nrep >>= 1;

    // workspace layout (floats)
    float* ws  = (float*)d_ws;
    float* h1  = ws;                          // N*4
    float* h2  = h1 + (size_t)N * 4;          // N*4
    float* cs1 = h2 + (size_t)N * 4;          // N*8
    float* cs2 = cs1 + (size_t)N * 8;         // N*8
    float* qcs = cs2 + (size_t)N * 8;         // 64 (48 used)
    float* RS1 = qcs + 64;                    // nrep*N*5 (zeroed)
    float* RS2 = RS1 + (size_t)nrep * N * 5;  // nrep*N*5 (zeroed)

    hipMemsetAsync(RS1, 0, 2 * (size_t)nrep * N * 5 * sizeof(float), stream);

    const int B = 256;
    k_gru<<<(N + 15) / 16, B, 0, stream>>>(x, W_ih, W_hh, b_ih, b_hh, p1W, p1b,
                                           q1w, q2w, h1, cs1, qcs, N);

    k_msgf<<<(EN + B - 1) / B, B, 0, stream>>>(ei, ea, h1, cs1, a1W, qcs, RS1, nrep - 1, E, N);
    k_node1<<<(N + B - 1) / B, B, 0, stream>>>(RS1, nrep, h1, g1, be1, p2W, p2b, h2, cs2, N);

    k_msgf<<<(EN + B - 1) / B, B, 0, stream>>>(ei, ea, h2, cs2, a2W, qcs + 24, RS2, nrep - 1, E, N);
    k_node2<<<(N + B - 1) / B, B, 0, stream>>>(RS2, nrep, h2, g2, be2, rW, rb, out, N);
}